// Round 1
// baseline (549.153 us; speedup 1.0000x reference)
//
#include <hip/hip_runtime.h>
#include <math.h>

// Problem constants (from reference)
#define NQ     65536     // queue size K
#define DIM    256       // feature dim
#define NBATCH 512       // batch N
#define KNN    200
#define NCLS   1000

// Output layout (all values stored as f32):
// out[0]                       accuracy
// out[1 .. 1+NQ*DIM)           new_queue_features
// out[1+NQ*DIM .. +NQ)         new_queue_labels (as float values)
// out[1+NQ*DIM+NQ]             new_queue_ptr (as float value)

// ---------------------------------------------------------------------------
// 1. Copy / queue-update kernel. Also zero-inits accuracy and writes new ptr.
// ---------------------------------------------------------------------------
__global__ __launch_bounds__(256) void copy_kernel(
    const float* __restrict__ feat, const int* __restrict__ labels,
    const float* __restrict__ qf, const int* __restrict__ ql,
    const int* __restrict__ qptr, float* __restrict__ out)
{
  const long long NFEAT = (long long)NQ * DIM;      // 16777216
  long long idx = (long long)blockIdx.x * blockDim.x + threadIdx.x;
  int ptr = qptr[0];

  if (idx < NFEAT) {
    long long row = idx >> 8;            // / DIM
    int col = (int)(idx & (DIM - 1));
    int d = ((int)row - ptr) & (NQ - 1); // (row - ptr) mod NQ
    float v = (d < NBATCH) ? feat[(long long)d * DIM + col] : qf[idx];
    out[1 + idx] = v;
  } else if (idx < NFEAT + NQ) {
    int i = (int)(idx - NFEAT);
    int d = (i - ptr) & (NQ - 1);
    int v = (d < NBATCH) ? labels[d] : ql[i];
    out[1 + NFEAT + i] = (float)v;
  }
  if (idx == 0) {
    out[0] = 0.0f;                                        // accuracy accumulator
    out[1 + NFEAT + NQ] = (float)((ptr + NBATCH) & (NQ - 1));  // new ptr
  }
}

// ---------------------------------------------------------------------------
// 2. f32 GEMM: C[nrows x NQ] = A[rows row0..] (512x256) * B^T (65536x256)
//    64x64 tile per block, 16x16 threads, 4x4 micro-tile, BK=16.
// ---------------------------------------------------------------------------
#define BK  16
#define LDT 68   // padded LDS row stride (floats): 16B-aligned rows, 2-way-free banks

__global__ __launch_bounds__(256) void gemm_kernel(
    const float* __restrict__ A, const float* __restrict__ B,
    float* __restrict__ C, int row0)
{
  __shared__ float As[BK][LDT];
  __shared__ float Bs[BK][LDT];

  int tid = threadIdx.x;
  int tx = tid & 15, ty = tid >> 4;
  int rowbase = row0 + blockIdx.y * 64;   // into A (global rows, < 512)
  int colbase = blockIdx.x * 64;          // into B rows (queue index)

  int lr = tid >> 2;           // 0..63   loader row within tile
  int lc = (tid & 3) << 2;     // 0,4,8,12 loader k-offset

  float acc[4][4] = {};

  for (int kk = 0; kk < DIM; kk += BK) {
    float4 a4 = *(const float4*)(A + (long long)(rowbase + lr) * DIM + kk + lc);
    float4 b4 = *(const float4*)(B + (long long)(colbase + lr) * DIM + kk + lc);
    As[lc + 0][lr] = a4.x; As[lc + 1][lr] = a4.y;
    As[lc + 2][lr] = a4.z; As[lc + 3][lr] = a4.w;
    Bs[lc + 0][lr] = b4.x; Bs[lc + 1][lr] = b4.y;
    Bs[lc + 2][lr] = b4.z; Bs[lc + 3][lr] = b4.w;
    __syncthreads();
#pragma unroll
    for (int k = 0; k < BK; ++k) {
      float4 av = *(const float4*)&As[k][ty << 2];
      float4 bv = *(const float4*)&Bs[k][tx << 2];
      float a[4] = {av.x, av.y, av.z, av.w};
      float b[4] = {bv.x, bv.y, bv.z, bv.w};
#pragma unroll
      for (int i = 0; i < 4; ++i)
#pragma unroll
        for (int j = 0; j < 4; ++j)
          acc[i][j] = fmaf(a[i], b[j], acc[i][j]);
    }
    __syncthreads();
  }

  // write C (local rows relative to row0)
  int crow = blockIdx.y * 64 + (ty << 2);
  int ccol = colbase + (tx << 2);
#pragma unroll
  for (int i = 0; i < 4; ++i) {
    float4 o = {acc[i][0], acc[i][1], acc[i][2], acc[i][3]};
    *(float4*)(C + (long long)(crow + i) * NQ + ccol) = o;
  }
}

// ---------------------------------------------------------------------------
// 3. Per-row top-200 selection + weighted vote + argmax + accuracy add.
//    One block (256 threads) per sample row.
// ---------------------------------------------------------------------------
#define NB  2048
#define CAP 4096

__global__ __launch_bounds__(256) void select_kernel(
    const float* __restrict__ sims,     // [nrows x NQ] (local rows)
    const int* __restrict__ labels,     // [512]
    const int* __restrict__ qlab,       // [65536] ORIGINAL queue labels
    float* __restrict__ out_acc, int row0, float inv_n)
{
  __shared__ int   hist[NB];
  __shared__ int   seg[256];
  __shared__ float candV[CAP];
  __shared__ int   candI[CAP];
  __shared__ float votes[NCLS];
  __shared__ float rv[256];
  __shared__ int   ri[256];
  __shared__ int   s_b, s_cnt;

  int tid = threadIdx.x;
  int grow = row0 + blockIdx.x;                    // global sample row
  const float* srow = sims + (long long)blockIdx.x * NQ;

  // --- pass 1: histogram of sims in [-1,1] over 2048 bins ---
  for (int i = tid; i < NB; i += 256) hist[i] = 0;
  __syncthreads();
  for (int i = tid; i < NQ; i += 256) {
    float v = srow[i];
    int b = (int)((v + 1.0f) * (NB * 0.5f));
    b = b < 0 ? 0 : (b > NB - 1 ? NB - 1 : b);
    atomicAdd(&hist[b], 1);
  }
  __syncthreads();

  // --- find boundary bin b* = max b with count(bins >= b) >= KNN ---
  {
    int s = 0;
#pragma unroll
    for (int i = 0; i < 8; ++i) s += hist[tid * 8 + i];
    seg[tid] = s;
  }
  __syncthreads();
  if (tid == 0) {
    int run = 0;
    for (int t = 255; t >= 0; --t) { int tmp = seg[t]; seg[t] = run; run += tmp; }
    s_b = 0; s_cnt = 0;
  }
  __syncthreads();
  {
    int run = seg[tid];   // count strictly above this 8-bin segment
    for (int i = tid * 8 + 7; i >= tid * 8; --i) {
      run += hist[i];     // run = C(i) = count in bins >= i
      if (run >= KNN) { atomicMax(&s_b, i); break; }
    }
  }
  __syncthreads();
  int bstar = s_b;

  // --- pass 2: collect candidates (value, index) with bin >= b* ---
  for (int i = tid; i < NQ; i += 256) {
    float v = srow[i];
    int b = (int)((v + 1.0f) * (NB * 0.5f));
    b = b < 0 ? 0 : (b > NB - 1 ? NB - 1 : b);
    if (b >= bstar) {
      int p = atomicAdd(&s_cnt, 1);
      if (p < CAP) { candV[p] = v; candI[p] = i; }
    }
  }
  __syncthreads();
  int Cn = s_cnt < CAP ? s_cnt : CAP;

  // --- bitonic sort (value desc, index asc) on next-pow2 size ---
  int P = 256; while (P < Cn) P <<= 1;
  for (int i = tid; i < P; i += 256)
    if (i >= Cn) { candV[i] = -INFINITY; candI[i] = 0x7fffffff; }
  __syncthreads();
  for (int k = 2; k <= P; k <<= 1) {
    for (int j = k >> 1; j > 0; j >>= 1) {
      for (int i = tid; i < P; i += 256) {
        int ixj = i ^ j;
        if (ixj > i) {
          float va = candV[i], vb = candV[ixj];
          int ia = candI[i], ib = candI[ixj];
          bool aFirst = (va > vb) || (va == vb && ia < ib);
          bool up = ((i & k) == 0);
          if (up ? !aFirst : aFirst) {
            candV[i] = vb; candV[ixj] = va;
            candI[i] = ib; candI[ixj] = ia;
          }
        }
      }
      __syncthreads();
    }
  }

  // --- weighted vote over top-KNN ---
  for (int c = tid; c < NCLS; c += 256) votes[c] = 0.0f;
  __syncthreads();
  for (int i = tid; i < KNN; i += 256) {
    float w = expf(candV[i] / 0.07f);
    int lbl = qlab[candI[i]];
    atomicAdd(&votes[lbl], w);
  }
  __syncthreads();

  // --- argmax (lowest index on tie) ---
  float bv = -1.0f; int bi = 0x7fffffff;
  for (int c = tid; c < NCLS; c += 256) {
    float v = votes[c];
    if (v > bv || (v == bv && c < bi)) { bv = v; bi = c; }
  }
  rv[tid] = bv; ri[tid] = bi;
  __syncthreads();
  for (int s = 128; s > 0; s >>= 1) {
    if (tid < s) {
      if (rv[tid + s] > rv[tid] ||
          (rv[tid + s] == rv[tid] && ri[tid + s] < ri[tid])) {
        rv[tid] = rv[tid + s]; ri[tid] = ri[tid + s];
      }
    }
    __syncthreads();
  }
  if (tid == 0) {
    if (ri[0] == labels[grow]) atomicAdd(out_acc, inv_n);
  }
}

// ---------------------------------------------------------------------------
extern "C" void kernel_launch(void* const* d_in, const int* in_sizes, int n_in,
                              void* d_out, int out_size, void* d_ws, size_t ws_size,
                              hipStream_t stream)
{
  const float* features = (const float*)d_in[0];
  const int*   labels   = (const int*)d_in[1];
  const float* qfeat    = (const float*)d_in[2];
  const int*   qlab     = (const int*)d_in[3];
  const int*   qptr     = (const int*)d_in[4];
  float* out = (float*)d_out;

  int nbatch = in_sizes[0] / DIM;           // 512
  float inv_n = 1.0f / (float)nbatch;

  // 1. queue update copy (+ accuracy zero-init + new ptr)
  {
    long long total = (long long)NQ * DIM + NQ;   // 16842752
    int blocks = (int)((total + 255) / 256);
    copy_kernel<<<blocks, 256, 0, stream>>>(features, labels, qfeat, qlab, qptr, out);
  }

  // 2/3. sim GEMM + selection, chunked over sample rows to fit d_ws
  long long ws_rows = (long long)(ws_size / ((size_t)NQ * sizeof(float)));
  int chunk = (int)((ws_rows / 64) * 64);
  if (chunk <= 0) chunk = 64;               // hope ws >= 16 MB
  if (chunk > nbatch) chunk = nbatch;

  for (int row0 = 0; row0 < nbatch; row0 += chunk) {
    int nrows = nbatch - row0; if (nrows > chunk) nrows = chunk;
    dim3 ggrid(NQ / 64, nrows / 64);
    gemm_kernel<<<ggrid, 256, 0, stream>>>(features, qfeat, (float*)d_ws, row0);
    select_kernel<<<nrows, 256, 0, stream>>>((const float*)d_ws, labels, qlab,
                                             out, row0, inv_n);
  }
}

// Round 2
// 330.937 us; speedup vs baseline: 1.6594x; 1.6594x over previous
//
#include <hip/hip_runtime.h>
#include <math.h>

// Problem constants
#define NQ     65536
#define DIM    256
#define NBATCH 512
#define KNN    200
#define NCLS   1000

typedef unsigned short u16;
typedef __attribute__((ext_vector_type(8))) short short8;   // 8 bf16 (4 VGPRs)
typedef __attribute__((ext_vector_type(4))) float f32x4;    // MFMA acc

// Output layout (f32 values):
// out[0] accuracy | out[1..1+NQ*DIM) features | [..+NQ) labels | [last] ptr

// ---------------------------------------------------------------------------
// helpers
// ---------------------------------------------------------------------------
__device__ __forceinline__ u16 f2bf(float x) {
  unsigned u = __float_as_uint(x);
  return (u16)((u + 0x7FFFu + ((u >> 16) & 1u)) >> 16);
}
__device__ __forceinline__ float bf2f(u16 h) {
  return __uint_as_float(((unsigned)h) << 16);
}
__device__ __forceinline__ void load_lds16(const void* g, void* l) {
  __builtin_amdgcn_global_load_lds(
      (const __attribute__((address_space(1))) unsigned int*)g,
      (__attribute__((address_space(3))) unsigned int*)l, 16, 0, 0);
}

// ---------------------------------------------------------------------------
// 0. prep: split A (features) and B (queue_features) into bf16 hi/lo; zero acc
// ---------------------------------------------------------------------------
__global__ __launch_bounds__(256) void prep_kernel(
    const float* __restrict__ feat, const float* __restrict__ qf,
    u16* __restrict__ Bhi, u16* __restrict__ Blo,
    u16* __restrict__ Ahi, u16* __restrict__ Alo, float* __restrict__ out)
{
  int idx = blockIdx.x * 256 + threadIdx.x;           // float4 index
  const int NB4 = NQ * DIM / 4;                       // 4194304
  const int NA4 = NBATCH * DIM / 4;                   // 32768
  if (idx < NB4) {
    float4 v = ((const float4*)qf)[idx];
    ushort4 h, l;
    h.x = f2bf(v.x); l.x = f2bf(v.x - bf2f(h.x));
    h.y = f2bf(v.y); l.y = f2bf(v.y - bf2f(h.y));
    h.z = f2bf(v.z); l.z = f2bf(v.z - bf2f(h.z));
    h.w = f2bf(v.w); l.w = f2bf(v.w - bf2f(h.w));
    ((ushort4*)Bhi)[idx] = h;
    ((ushort4*)Blo)[idx] = l;
  } else if (idx < NB4 + NA4) {
    int j = idx - NB4;
    float4 v = ((const float4*)feat)[j];
    ushort4 h, l;
    h.x = f2bf(v.x); l.x = f2bf(v.x - bf2f(h.x));
    h.y = f2bf(v.y); l.y = f2bf(v.y - bf2f(h.y));
    h.z = f2bf(v.z); l.z = f2bf(v.z - bf2f(h.z));
    h.w = f2bf(v.w); l.w = f2bf(v.w - bf2f(h.w));
    ((ushort4*)Ahi)[j] = h;
    ((ushort4*)Alo)[j] = l;
  }
  if (idx == 0) out[0] = 0.0f;
}

// ---------------------------------------------------------------------------
// 1. split-bf16 MFMA GEMM: C[mrows x NQ] = A * B^T, exact to ~3e-7
//    128x128 tile, BK=32, 4 waves, each wave 64x64 via 4x4 16x16x32 MFMAs,
//    4 chained MFMAs per position (hi*hi + hi*lo + lo*hi + lo*lo).
// ---------------------------------------------------------------------------
#define GM 128
#define GK 32

__global__ __launch_bounds__(256) void gemm_mfma(
    const u16* __restrict__ Ahi, const u16* __restrict__ Alo,
    const u16* __restrict__ Bhi, const u16* __restrict__ Blo,
    float* __restrict__ C)
{
  __shared__ u16 sA[2][GM][GK];   // [hi/lo][row][k]  8 KB each
  __shared__ u16 sB[2][GM][GK];

  const int tid  = threadIdx.x;
  const int wave = tid >> 6, lane = tid & 63;
  const int bm = blockIdx.x, bn = blockIdx.y;

  // staging role: one wave per (matrix, hi/lo) tile; 8 x 16B-lds-loads each
  const u16* srcBase;
  u16* ldsBase;
  if (wave == 0)      { srcBase = Ahi + (size_t)bm * GM * DIM; ldsBase = &sA[0][0][0]; }
  else if (wave == 1) { srcBase = Alo + (size_t)bm * GM * DIM; ldsBase = &sA[1][0][0]; }
  else if (wave == 2) { srcBase = Bhi + (size_t)bn * GM * DIM; ldsBase = &sB[0][0][0]; }
  else                { srcBase = Blo + (size_t)bn * GM * DIM; ldsBase = &sB[1][0][0]; }
  const u16* src = srcBase + (lane >> 2) * DIM + (lane & 3) * 8;

  const int wm = (wave & 1) * 64, wn = (wave >> 1) * 64;
  const int fr = lane & 15;   // fragment row (m or n)
  const int fq = lane >> 4;   // quad: k = fq*8 + j

  f32x4 acc[4][4] = {};

  for (int kk = 0; kk < DIM; kk += GK) {
    const u16* s = src + kk;
#pragma unroll
    for (int g = 0; g < 8; ++g)
      load_lds16(s + g * 16 * DIM, ldsBase + g * 512);
    __syncthreads();

    short8 ah[4], al[4], bh[4], bl[4];
#pragma unroll
    for (int i = 0; i < 4; ++i) {
      ah[i] = *(const short8*)&sA[0][wm + i * 16 + fr][fq * 8];
      al[i] = *(const short8*)&sA[1][wm + i * 16 + fr][fq * 8];
      bh[i] = *(const short8*)&sB[0][wn + i * 16 + fr][fq * 8];
      bl[i] = *(const short8*)&sB[1][wn + i * 16 + fr][fq * 8];
    }
#pragma unroll
    for (int i = 0; i < 4; ++i)
#pragma unroll
      for (int j = 0; j < 4; ++j) {
        acc[i][j] = __builtin_amdgcn_mfma_f32_16x16x32_bf16(ah[i], bh[j], acc[i][j], 0, 0, 0);
        acc[i][j] = __builtin_amdgcn_mfma_f32_16x16x32_bf16(ah[i], bl[j], acc[i][j], 0, 0, 0);
        acc[i][j] = __builtin_amdgcn_mfma_f32_16x16x32_bf16(al[i], bh[j], acc[i][j], 0, 0, 0);
        acc[i][j] = __builtin_amdgcn_mfma_f32_16x16x32_bf16(al[i], bl[j], acc[i][j], 0, 0, 0);
      }
    __syncthreads();
  }

  // epilogue: D row = fq*4 + r (m side), col = fr (n side)  [m89-verified]
  const int crow = bm * GM + wm + fq * 4;
  const int ccol = bn * GM + wn + fr;
#pragma unroll
  for (int i = 0; i < 4; ++i)
#pragma unroll
    for (int j = 0; j < 4; ++j)
#pragma unroll
      for (int r = 0; r < 4; ++r)
        C[(size_t)(crow + i * 16 + r) * NQ + ccol + j * 16] = acc[i][j][r];
}

// ---------------------------------------------------------------------------
// 2. select v2: one 1024-thread block per row; whole row register-resident.
// ---------------------------------------------------------------------------
#define NBINS 2048
#define CAP   1024

__global__ __launch_bounds__(1024) void select_kernel(
    const float* __restrict__ sims, const int* __restrict__ labels,
    const int* __restrict__ qlab, float* __restrict__ out,
    int row0, float inv_n)
{
  __shared__ int   hist[NBINS];
  __shared__ int   seg[256];
  __shared__ float candV[CAP];
  __shared__ int   candI[CAP];
  __shared__ float votes[NCLS];
  __shared__ int   s_b, s_cnt;
  __shared__ unsigned long long s_best;

  const int tid = threadIdx.x;
  const int grow = row0 + blockIdx.x;
  const float4* srow = (const float4*)(sims + (size_t)blockIdx.x * NQ);

  // load entire row into registers (16 float4 = 64 values / thread)
  float4 v[16];
#pragma unroll
  for (int t = 0; t < 16; ++t) v[t] = srow[t * 1024 + tid];

  for (int i = tid; i < NBINS; i += 1024) hist[i] = 0;
  if (tid == 0) { s_b = 0; s_cnt = 0; s_best = 0ull; }
  __syncthreads();

  // histogram from registers
#pragma unroll
  for (int t = 0; t < 16; ++t) {
    float w[4] = {v[t].x, v[t].y, v[t].z, v[t].w};
#pragma unroll
    for (int c = 0; c < 4; ++c) {
      int b = (int)((w[c] + 1.0f) * (NBINS * 0.5f));
      b = b < 0 ? 0 : (b > NBINS - 1 ? NBINS - 1 : b);
      atomicAdd(&hist[b], 1);
    }
  }
  __syncthreads();

  // 256 segment sums of 8 bins each, then parallel inclusive SUFFIX scan
  if (tid < 256) {
    int s = 0;
#pragma unroll
    for (int i = 0; i < 8; ++i) s += hist[tid * 8 + i];
    seg[tid] = s;
  }
  __syncthreads();
  for (int off = 1; off < 256; off <<= 1) {
    int t = 0;
    if (tid < 256 && tid + off < 256) t = seg[tid + off];
    __syncthreads();
    if (tid < 256) seg[tid] += t;
    __syncthreads();
  }
  // boundary bin b* = max b with count(bins >= b) >= KNN
  if (tid < 256) {
    int run = (tid < 255) ? seg[tid + 1] : 0;
    for (int i = tid * 8 + 7; i >= tid * 8; --i) {
      run += hist[i];
      if (run >= KNN) { atomicMax(&s_b, i); break; }
    }
  }
  __syncthreads();
  const int bstar = s_b;

  // collect candidates from registers
#pragma unroll
  for (int t = 0; t < 16; ++t) {
    float w[4] = {v[t].x, v[t].y, v[t].z, v[t].w};
#pragma unroll
    for (int c = 0; c < 4; ++c) {
      int b = (int)((w[c] + 1.0f) * (NBINS * 0.5f));
      b = b < 0 ? 0 : (b > NBINS - 1 ? NBINS - 1 : b);
      if (b >= bstar) {
        int p = atomicAdd(&s_cnt, 1);
        if (p < CAP) { candV[p] = w[c]; candI[p] = 4 * (t * 1024 + tid) + c; }
      }
    }
  }
  __syncthreads();
  int Cn = s_cnt < CAP ? s_cnt : CAP;

  // bitonic sort (value desc, index asc) — matches lax.top_k tie semantics
  int P = 256; while (P < Cn) P <<= 1;
  if (tid < P && tid >= Cn) { candV[tid] = -INFINITY; candI[tid] = 0x7fffffff; }
  __syncthreads();
  for (int k = 2; k <= P; k <<= 1) {
    for (int j = k >> 1; j > 0; j >>= 1) {
      if (tid < P) {
        int i = tid, ixj = i ^ j;
        if (ixj > i) {
          float va = candV[i], vb = candV[ixj];
          int ia = candI[i], ib = candI[ixj];
          bool aFirst = (va > vb) || (va == vb && ia < ib);
          bool up = ((i & k) == 0);
          if (up ? !aFirst : aFirst) {
            candV[i] = vb; candV[ixj] = va;
            candI[i] = ib; candI[ixj] = ia;
          }
        }
      }
      __syncthreads();
    }
  }

  // weighted vote over top-KNN
  for (int c = tid; c < NCLS; c += 1024) votes[c] = 0.0f;
  __syncthreads();
  if (tid < KNN) {
    float w = expf(candV[tid] * (1.0f / 0.07f));
    atomicAdd(&votes[qlab[candI[tid]]], w);
  }
  __syncthreads();

  // argmax, lowest index on tie: key = (bits(v)<<32) | ~cls, wave-reduce + atomicMax
  unsigned long long key = 0ull;
  if (tid < NCLS)
    key = ((unsigned long long)__float_as_uint(votes[tid]) << 32) |
          (unsigned long long)(0xFFFFFFFFu - (unsigned)tid);
  for (int off = 32; off > 0; off >>= 1) {
    unsigned long long o = __shfl_down(key, off, 64);
    if (o > key) key = o;
  }
  if ((tid & 63) == 0) atomicMax(&s_best, key);
  __syncthreads();
  if (tid == 0) {
    int cls = (int)(0xFFFFFFFFu - (unsigned)(s_best & 0xFFFFFFFFull));
    if (cls == labels[grow]) atomicAdd(out, inv_n);
  }
}

// ---------------------------------------------------------------------------
// 3. final copy / queue update (runs LAST: overwrites the B-split staging
//    that prep parked in out's feature region). Also writes new ptr.
// ---------------------------------------------------------------------------
__global__ __launch_bounds__(256) void copy_kernel(
    const float* __restrict__ feat, const int* __restrict__ labels,
    const float* __restrict__ qf, const int* __restrict__ ql,
    const int* __restrict__ qptr, float* __restrict__ out)
{
  const long long NFEAT = (long long)NQ * DIM;
  long long idx = (long long)blockIdx.x * blockDim.x + threadIdx.x;
  int ptr = qptr[0];

  if (idx < NFEAT) {
    long long row = idx >> 8;
    int col = (int)(idx & (DIM - 1));
    int d = ((int)row - ptr) & (NQ - 1);
    float v = (d < NBATCH) ? feat[(long long)d * DIM + col] : qf[idx];
    out[1 + idx] = v;
  } else if (idx < NFEAT + NQ) {
    int i = (int)(idx - NFEAT);
    int d = (i - ptr) & (NQ - 1);
    int v = (d < NBATCH) ? labels[d] : ql[i];
    out[1 + NFEAT + i] = (float)v;
  }
  if (idx == 0)
    out[1 + NFEAT + NQ] = (float)((ptr + NBATCH) & (NQ - 1));
}

// ---------------------------------------------------------------------------
extern "C" void kernel_launch(void* const* d_in, const int* in_sizes, int n_in,
                              void* d_out, int out_size, void* d_ws, size_t ws_size,
                              hipStream_t stream)
{
  const float* features = (const float*)d_in[0];
  const int*   labels   = (const int*)d_in[1];
  const float* qfeat    = (const float*)d_in[2];
  const int*   qlab     = (const int*)d_in[3];
  const int*   qptr     = (const int*)d_in[4];
  float* out = (float*)d_out;

  int nbatch = in_sizes[0] / DIM;             // 512
  float inv_n = 1.0f / (float)nbatch;

  // B hi/lo staged in out's feature region (64 MiB), 16B-aligned at out+4;
  // overwritten by copy_kernel at the end. A hi/lo live in the ws tail.
  u16* Bhi = (u16*)(out + 4);
  u16* Blo = Bhi + (size_t)NQ * DIM;

  // row chunking so sims + A-splits fit in ws (ws >= 128 MiB known)
  size_t aBytes = (size_t)nbatch * DIM * 2 * 2;               // 512 KiB
  int chunk = ((size_t)nbatch * NQ * 4 + aBytes <= ws_size) ? nbatch : nbatch / 2;
  float* sims = (float*)d_ws;
  u16* Ahi = (u16*)((char*)d_ws + (size_t)chunk * NQ * 4);
  u16* Alo = Ahi + (size_t)nbatch * DIM;

  // 0. prep (also zeroes out[0])
  {
    int total4 = NQ * DIM / 4 + nbatch * DIM / 4;
    prep_kernel<<<(total4 + 255) / 256, 256, 0, stream>>>(
        features, qfeat, Bhi, Blo, Ahi, Alo, out);
  }

  // 1/2. GEMM + select per chunk
  for (int row0 = 0; row0 < nbatch; row0 += chunk) {
    dim3 ggrid(chunk / GM, NQ / GM);          // x fastest: M-tiles share B tile
    gemm_mfma<<<ggrid, 256, 0, stream>>>(
        Ahi + (size_t)row0 * DIM, Alo + (size_t)row0 * DIM, Bhi, Blo, sims);
    select_kernel<<<chunk, 1024, 0, stream>>>(sims, labels, qlab, out, row0, inv_n);
  }

  // 3. queue update (must be last: reuses out's feature region)
  copy_kernel<<<((long long)NQ * DIM + NQ + 255) / 256, 256, 0, stream>>>(
      features, labels, qfeat, qlab, qptr, out);
}